// Round 9
// baseline (1364.787 us; speedup 1.0000x reference)
//
#include <hip/hip_runtime.h>
#include <hip/hip_bf16.h>
#include <stdint.h>

#define DIM    4096
#define NH     32
#define NKVH   8
#define HD     128
#define SEQ    2048
#define BATCH  2
#define MTOT   (BATCH*SEQ)      // 4096
#define SCALE  0.08838834764831845f

typedef __bf16 bf16_t;
typedef __bf16 bf16x8 __attribute__((ext_vector_type(8)));
typedef float  f32x4  __attribute__((ext_vector_type(4)));

#define AS1 __attribute__((address_space(1)))
#define AS3 __attribute__((address_space(3)))

__device__ __forceinline__ void gload_lds16(const void* g, void* l) {
    __builtin_amdgcn_global_load_lds((const AS1 void*)g, (AS3 void*)l, 16, 0, 0);
}

// ---------------- fused f32 -> bf16 convert: x|wq|wk|wv|wo ----------------
// writes xb (4M f4) then wb (wq 4M | wk 1M | wv 1M | wo 4M) contiguously.
__global__ __launch_bounds__(256)
void cvt_all(const float* __restrict__ x,
             const float* __restrict__ wq, const float* __restrict__ wk,
             const float* __restrict__ wv, const float* __restrict__ wo,
             bf16_t* __restrict__ out) {
    const int nx = MTOT * DIM / 4;           // 4M
    const int n0 = DIM * DIM / 4;            // 4M
    const int n1 = NKVH * HD * DIM / 4;      // 1M
    const int n2 = NKVH * HD * DIM / 4;      // 1M
    const int n3 = DIM * DIM / 4;            // 4M
    const int ntot = nx + n0 + n1 + n2 + n3;
    for (int i = blockIdx.x * blockDim.x + threadIdx.x; i < ntot;
         i += gridDim.x * blockDim.x) {
        const float* src;
        int k = i;
        if (k < nx) src = x;
        else if ((k -= nx) < n0) src = wq;
        else if ((k -= n0) < n1) src = wk;
        else if ((k -= n1) < n2) src = wv;
        else { k -= n2; src = wo; }
        float4 v = reinterpret_cast<const float4*>(src)[k];
        union { bf16_t b[4]; uint2 u; } t;
        t.b[0] = (bf16_t)v.x; t.b[1] = (bf16_t)v.y;
        t.b[2] = (bf16_t)v.z; t.b[3] = (bf16_t)v.w;
        reinterpret_cast<uint2*>(out)[i] = t.u;
    }
}

// ===== m97-style 128x128-tile GEMM: single-buffered 32 KiB LDS, 2 barriers
// per K-tile, 5 blocks/CU (VGPR=64; LDS is the only occupancy limit; more
// resident blocks -> more cross-block wave overlap filling barrier drains).
// 256 threads = 4 waves (2x2); wave tile 64x64 = 4x4 frags of 16x16x32.
// XOR chunk swizzle (c ^= r&7) via pre-swizzled global source + swizzled
// ds_read -> 0 bank conflicts.
// MODE 0: f32 out. MODE 3: fused QKV (rope Q/K, transpose V), NY=48.

template<int MODE>
__global__ __launch_bounds__(256, 5)
void gemm97(const bf16_t* __restrict__ A,
            const bf16_t* __restrict__ B0,
            float* __restrict__ outF,
            bf16_t* __restrict__ outQ,
            bf16_t* __restrict__ outK,
            bf16_t* __restrict__ outV,
            const float* __restrict__ cosT,
            const float* __restrict__ sinT) {
    __shared__ __align__(16) bf16_t As[128 * 64];
    __shared__ __align__(16) bf16_t Bs[128 * 64];

    const int tid = threadIdx.x;
    const int l = tid & 63;
    const int w = tid >> 6;           // 0..3
    const int wr = w >> 1, wc = w & 1;
    const int lr = l & 15, lg = l >> 4;

    const int rowBase = blockIdx.x * 128;
    const int ct = blockIdx.y;

    const bf16_t* Ap = A + (size_t)rowBase * DIM;
    const bf16_t* Bp = B0 + (size_t)ct * 128 * DIM;

    f32x4 acc[4][4] = {};

    for (int kt = 0; kt < DIM; kt += 64) {
        // stage A and B tiles (16 KB each): 4 gload_lds per operand
#pragma unroll
        for (int t2 = 0; t2 < 4; ++t2) {
            int s = t2 * 256 + tid;
            int r = s >> 3, c = s & 7;
            int src = r * DIM + kt + ((c ^ (r & 7)) * 8);
            gload_lds16(Ap + src, As + (size_t)(t2 * 256 + w * 64) * 8);
            gload_lds16(Bp + src, Bs + (size_t)(t2 * 256 + w * 64) * 8);
        }
        __syncthreads();   // vmcnt(0)+lgkm(0)+barrier: tile landed

#pragma unroll
        for (int kk = 0; kk < 2; ++kk) {
            bf16x8 a[4], b[4];
#pragma unroll
            for (int mi = 0; mi < 4; ++mi) {
                int r = wr * 64 + mi * 16 + lr;
                a[mi] = *(const bf16x8*)(As + r * 64 + ((kk * 4 + lg) ^ (r & 7)) * 8);
            }
#pragma unroll
            for (int ni = 0; ni < 4; ++ni) {
                int r = wc * 64 + ni * 16 + lr;
                b[ni] = *(const bf16x8*)(Bs + r * 64 + ((kk * 4 + lg) ^ (r & 7)) * 8);
            }
            __builtin_amdgcn_s_setprio(1);
#pragma unroll
            for (int mi = 0; mi < 4; ++mi)
#pragma unroll
                for (int ni = 0; ni < 4; ++ni)
                    acc[mi][ni] = __builtin_amdgcn_mfma_f32_16x16x32_bf16(
                        a[mi], b[ni], acc[mi][ni], 0, 0, 0);
            __builtin_amdgcn_s_setprio(0);
        }
        __syncthreads();   // all reads drained: safe to overwrite buffer
    }

    // ---- epilogue ----
#pragma unroll
    for (int mi = 0; mi < 4; ++mi) {
        int gmBase = rowBase + wr * 64 + mi * 16 + lg * 4;
#pragma unroll
        for (int ni = 0; ni < 4; ++ni) {
            f32x4 v4 = acc[mi][ni];
            int gn = ct * 128 + wc * 64 + ni * 16 + lr;
            if (MODE == 0) {
#pragma unroll
                for (int i = 0; i < 4; ++i)
                    outF[(size_t)(gmBase + i) * DIM + gn] = v4[i];
            } else { // MODE 3: fused QKV, N = 6144
                if (gn < 4096) {          // Q rope -> Qr[b][h][s][d]
                    int h = gn >> 7, d = gn & 127, pi2 = d >> 1;
#pragma unroll
                    for (int i = 0; i < 4; ++i) {
                        float v = v4[i];
                        float pvv = __shfl_xor(v, 1);
                        int gm = gmBase + i;
                        int bb = gm >> 11, sidx = gm & (SEQ - 1);
                        float c = cosT[sidx * 64 + pi2], sn = sinT[sidx * 64 + pi2];
                        float o = (d & 1) ? (pvv * sn + v * c) : (v * c - pvv * sn);
                        outQ[((size_t)(bb * NH + h) * SEQ + sidx) * HD + d] = (bf16_t)o;
                    }
                } else if (gn < 5120) {   // K rope -> Kr[b][kvh][s][d]
                    int kn = gn - 4096;
                    int h = kn >> 7, d = kn & 127, pi2 = d >> 1;
#pragma unroll
                    for (int i = 0; i < 4; ++i) {
                        float v = v4[i];
                        float pvv = __shfl_xor(v, 1);
                        int gm = gmBase + i;
                        int bb = gm >> 11, sidx = gm & (SEQ - 1);
                        float c = cosT[sidx * 64 + pi2], sn = sinT[sidx * 64 + pi2];
                        float o = (d & 1) ? (pvv * sn + v * c) : (v * c - pvv * sn);
                        outK[((size_t)(bb * NKVH + h) * SEQ + sidx) * HD + d] = (bf16_t)o;
                    }
                } else {                  // V transpose -> Vt[b][kvh][d][s]
                    int vn = gn - 5120;
                    int kvh = vn >> 7, d = vn & 127;
#pragma unroll
                    for (int i = 0; i < 4; ++i) {
                        float dummy = __shfl_xor(v4[i], 1); (void)dummy;
                        int gm = gmBase + i;
                        int bb = gm >> 11, sidx = gm & (SEQ - 1);
                        outV[((size_t)(bb * NKVH + kvh) * HD + d) * SEQ + sidx] = (bf16_t)v4[i];
                    }
                }
            }
        }
    }
}

// ---------------- flash attention (causal, GQA) ---------------- (R7 version)
__global__ __launch_bounds__(256, 2)
void attn_fwd(const bf16_t* __restrict__ Qr,
              const bf16_t* __restrict__ Kr,
              const bf16_t* __restrict__ Vt,
              bf16_t* __restrict__ Ob) {
    __shared__ __align__(16) bf16_t Ks[2][64 * 128];   // [kv][d], swizzled
    __shared__ __align__(16) bf16_t Vs[2][128 * 64];   // [d][kv], swizzled
    __shared__ __align__(16) bf16_t Ps[4][32 * 64];    // per-wave P, swizzled

    const int tid = threadIdx.x;
    const int l  = tid & 63;
    const int w  = tid >> 6;
    const int lr = l & 15, lg = l >> 4;
    const int e  = lr & 7;

    const int qt  = 15 - (blockIdx.x >> 6);
    const int bh  = blockIdx.x & 63;
    const int b   = bh >> 5;
    const int h   = bh & 31;
    const int kvh = h >> 2;
    const int q0  = qt * 128;
    const int nt  = 2 * qt + 2;
    const int qmin = q0 + w * 32;

    const bf16_t* kbase = Kr + (size_t)(b * NKVH + kvh) * SEQ * HD;
    const bf16_t* vbase = Vt + (size_t)(b * NKVH + kvh) * HD * SEQ;

    bf16x8 qf[2][4];
    const bf16_t* qp = Qr + ((size_t)(b * NH + h) * SEQ + qmin + lr) * HD;
#pragma unroll
    for (int mi = 0; mi < 2; ++mi)
#pragma unroll
        for (int kk = 0; kk < 4; ++kk)
            qf[mi][kk] = *(const bf16x8*)(qp + (size_t)mi * 16 * HD + kk * 32 + lg * 8);

    f32x4 oacc[2][8] = {};
    float mrow[2] = {-1e30f, -1e30f};
    float lsum[2] = {0.f, 0.f};

#pragma unroll
    for (int t2 = 0; t2 < 4; ++t2) {
        int s = t2 * 256 + tid;
        { int r = s >> 4, g = (s & 15) ^ (r & 7);
          gload_lds16(kbase + (size_t)r * HD + g * 8,
                      &Ks[0][(size_t)(t2 * 256 + w * 64) * 8]); }
        { int r = s >> 3, g = (s & 7) ^ (r & 7);
          gload_lds16(vbase + (size_t)r * SEQ + g * 8,
                      &Vs[0][(size_t)(t2 * 256 + w * 64) * 8]); }
    }
    __syncthreads();

    int cur = 0;
    for (int t = 0; t < nt; ++t) {
        if (t + 1 < nt) {
            const int kv1 = (t + 1) * 64;
#pragma unroll
            for (int t2 = 0; t2 < 4; ++t2) {
                int s = t2 * 256 + tid;
                { int r = s >> 4, g = (s & 15) ^ (r & 7);
                  gload_lds16(kbase + (size_t)(kv1 + r) * HD + g * 8,
                              &Ks[cur ^ 1][(size_t)(t2 * 256 + w * 64) * 8]); }
                { int r = s >> 3, g = (s & 7) ^ (r & 7);
                  gload_lds16(vbase + (size_t)r * SEQ + kv1 + g * 8,
                              &Vs[cur ^ 1][(size_t)(t2 * 256 + w * 64) * 8]); }
            }
        }

        const bool active = (t * 64) <= (qmin + 31);
        if (active) {
            const bool needMask = (t * 64 + 63) > qmin;

            f32x4 sf[2][4] = {};
#pragma unroll
            for (int kk = 0; kk < 4; ++kk)
#pragma unroll
                for (int nf = 0; nf < 4; ++nf) {
                    bf16x8 kf = *(const bf16x8*)(
                        &Ks[cur][(nf * 16 + lr) * 128 + ((kk * 4 + lg) ^ e) * 8]);
#pragma unroll
                    for (int mi = 0; mi < 2; ++mi)
                        sf[mi][nf] = __builtin_amdgcn_mfma_f32_16x16x32_bf16(
                            kf, qf[mi][kk], sf[mi][nf], 0, 0, 0);
                }

            float aO[2][4];
#pragma unroll
            for (int mi = 0; mi < 2; ++mi) {
                const int qrow = qmin + mi * 16 + lr;
                float mt = -1e30f;
#pragma unroll
                for (int nf = 0; nf < 4; ++nf)
#pragma unroll
                    for (int i = 0; i < 4; ++i) {
                        float sc = sf[mi][nf][i] * SCALE;
                        if (needMask && (t * 64 + nf * 16 + lg * 4 + i) > qrow)
                            sc = -1e30f;
                        sf[mi][nf][i] = sc;
                        mt = fmaxf(mt, sc);
                    }
                mt = fmaxf(mt, __shfl_xor(mt, 16));
                mt = fmaxf(mt, __shfl_xor(mt, 32));
                float mnew = fmaxf(mrow[mi], mt);
                float alpha = __expf(mrow[mi] - mnew);
                mrow[mi] = mnew;
                float rs = 0.f;
#pragma unroll
                for (int nf = 0; nf < 4; ++nf)
#pragma unroll
                    for (int i = 0; i < 4; ++i) {
                        float p = __expf(sf[mi][nf][i] - mnew);
                        sf[mi][nf][i] = p;
                        rs += p;
                    }
                rs += __shfl_xor(rs, 16);
                rs += __shfl_xor(rs, 32);
                lsum[mi] = lsum[mi] * alpha + rs;
#pragma unroll
                for (int i = 0; i < 4; ++i)
                    aO[mi][i] = __shfl(alpha, lg * 4 + i);
            }

#pragma unroll
            for (int mi = 0; mi < 2; ++mi)
#pragma unroll
                for (int df = 0; df < 8; ++df)
#pragma unroll
                    for (int i = 0; i < 4; ++i)
                        oacc[mi][df][i] *= aO[mi][i];

#pragma unroll
            for (int mi = 0; mi < 2; ++mi)
#pragma unroll
                for (int nf = 0; nf < 4; ++nf) {
                    union { bf16_t bb[4]; uint2 u; } pk;
#pragma unroll
                    for (int i = 0; i < 4; ++i) pk.bb[i] = (bf16_t)sf[mi][nf][i];
                    int addr = (mi * 16 + lr) * 64 +
                               (((nf * 2 + (lg >> 1)) ^ e) << 3) + (lg & 1) * 4;
                    *(uint2*)(&Ps[w][addr]) = pk.u;
                }
            asm volatile("s_waitcnt lgkmcnt(0)" ::: "memory");
            __builtin_amdgcn_sched_barrier(0);

            bf16x8 pf[2][2];
#pragma unroll
            for (int mi = 0; mi < 2; ++mi)
#pragma unroll
                for (int k2 = 0; k2 < 2; ++k2)
                    pf[mi][k2] = *(const bf16x8*)(
                        &Ps[w][(mi * 16 + lr) * 64 + ((k2 * 4 + lg) ^ e) * 8]);
#pragma unroll
            for (int df = 0; df < 8; ++df)
#pragma unroll
                for (int k2 = 0; k2 < 2; ++k2) {
                    bf16x8 vf = *(const bf16x8*)(
                        &Vs[cur][(df * 16 + lr) * 64 + ((k2 * 4 + lg) ^ e) * 8]);
#pragma unroll
                    for (int mi = 0; mi < 2; ++mi)
                        oacc[mi][df] = __builtin_amdgcn_mfma_f32_16x16x32_bf16(
                            pf[mi][k2], vf, oacc[mi][df], 0, 0, 0);
                }
        }
        __syncthreads();
        cur ^= 1;
    }

#pragma unroll
    for (int mi = 0; mi < 2; ++mi) {
        float ls[4];
#pragma unroll
        for (int i = 0; i < 4; ++i)
            ls[i] = 1.f / __shfl(lsum[mi], lg * 4 + i);
#pragma unroll
        for (int df = 0; df < 8; ++df)
#pragma unroll
            for (int i = 0; i < 4; ++i) {
                float o = oacc[mi][df][i] * ls[i];
                int gm = b * SEQ + qmin + mi * 16 + lg * 4 + i;
                int gn = h * HD + df * 16 + lr;
                Ob[(size_t)gm * DIM + gn] = (bf16_t)o;
            }
    }
}

// ---------------- launcher ----------------
extern "C" void kernel_launch(void* const* d_in, const int* in_sizes, int n_in,
                              void* d_out, int out_size, void* d_ws, size_t ws_size,
                              hipStream_t stream) {
    const float* x    = (const float*)d_in[0];
    const float* cosT = (const float*)d_in[1];
    const float* sinT = (const float*)d_in[2];
    const float* wq   = (const float*)d_in[3];
    const float* wk   = (const float*)d_in[4];
    const float* wv   = (const float*)d_in[5];
    const float* wo   = (const float*)d_in[6];

    bf16_t* p = (bf16_t*)d_ws;
    bf16_t* xb  = p; p += (size_t)MTOT * DIM;
    bf16_t* wb  = p; p += (size_t)(DIM + 2 * NKVH * HD + DIM) * DIM;  // wq|wk|wv|wo
    bf16_t* Qr  = p; p += (size_t)MTOT * DIM;
    bf16_t* Kr  = p; p += (size_t)BATCH * NKVH * SEQ * HD;
    bf16_t* Vt  = p; p += (size_t)BATCH * NKVH * HD * SEQ;
    bf16_t* Ob  = p; p += (size_t)MTOT * DIM;

    bf16_t* wob = wb + (size_t)(DIM + 2 * NKVH * HD) * DIM;  // wo region

    // one fused convert: x|wq|wk|wv|wo -> xb..wb (contiguous)
    cvt_all<<<2048, 256, 0, stream>>>(x, wq, wk, wv, wo, xb);

    // fused QKV: N = 4096 (Q) + 1024 (K) + 1024 (V) = 6144 -> 48 col tiles
    gemm97<3><<<dim3(32, 48), 256, 0, stream>>>(
        xb, wb, nullptr, Qr, Kr, Vt, cosT, sinT);

    attn_fwd<<<1024, 256, 0, stream>>>(Qr, Kr, Vt, Ob);

    gemm97<0><<<dim3(32, 32), 256, 0, stream>>>(
        Ob, wob, (float*)d_out, nullptr, nullptr, nullptr, nullptr, nullptr);
}

// Round 10
// 524.790 us; speedup vs baseline: 2.6006x; 2.6006x over previous
//
#include <hip/hip_runtime.h>
#include <hip/hip_bf16.h>
#include <stdint.h>

#define DIM    4096
#define NH     32
#define NKVH   8
#define HD     128
#define SEQ    2048
#define BATCH  2
#define MTOT   (BATCH*SEQ)      // 4096
#define SCALE  0.08838834764831845f

typedef __bf16 bf16_t;
typedef __bf16 bf16x8 __attribute__((ext_vector_type(8)));
typedef float  f32x4  __attribute__((ext_vector_type(4)));

#define AS1 __attribute__((address_space(1)))
#define AS3 __attribute__((address_space(3)))

__device__ __forceinline__ void gload_lds16(const void* g, void* l) {
    __builtin_amdgcn_global_load_lds((const AS1 void*)g, (AS3 void*)l, 16, 0, 0);
}

// ---------------- fused f32 -> bf16 convert: x|wq|wk|wv|wo ----------------
__global__ __launch_bounds__(256)
void cvt_all(const float* __restrict__ x,
             const float* __restrict__ wq, const float* __restrict__ wk,
             const float* __restrict__ wv, const float* __restrict__ wo,
             bf16_t* __restrict__ out) {
    const int nx = MTOT * DIM / 4;           // 4M
    const int n0 = DIM * DIM / 4;            // 4M
    const int n1 = NKVH * HD * DIM / 4;      // 1M
    const int n2 = NKVH * HD * DIM / 4;      // 1M
    const int n3 = DIM * DIM / 4;            // 4M
    const int ntot = nx + n0 + n1 + n2 + n3;
    for (int i = blockIdx.x * blockDim.x + threadIdx.x; i < ntot;
         i += gridDim.x * blockDim.x) {
        const float* src;
        int k = i;
        if (k < nx) src = x;
        else if ((k -= nx) < n0) src = wq;
        else if ((k -= n0) < n1) src = wk;
        else if ((k -= n1) < n2) src = wv;
        else { k -= n2; src = wo; }
        float4 v = reinterpret_cast<const float4*>(src)[k];
        union { bf16_t b[4]; uint2 u; } t;
        t.b[0] = (bf16_t)v.x; t.b[1] = (bf16_t)v.y;
        t.b[2] = (bf16_t)v.z; t.b[3] = (bf16_t)v.w;
        reinterpret_cast<uint2*>(out)[i] = t.u;
    }
}

// ===== m97-style 128x128-tile GEMM: single-buffered 32 KiB LDS, 2 barriers
// per K-tile, 3 blocks/CU. NOTE: 3 is the VGPR-feasible max — the kernel
// needs ~128 regs/wave (64 arch + 64 acc); __launch_bounds__(256,5) caps
// waves at ~102 regs and spills the accumulators to scratch (R9: WRITE_SIZE
// 53->773 MB, MfmaUtil 44->9.6%). Do not raise without register headroom.
// 256 threads = 4 waves (2x2); wave tile 64x64 = 4x4 frags of 16x16x32.
// XOR chunk swizzle (c ^= r&7) via pre-swizzled global source + swizzled
// ds_read -> 0 bank conflicts.
// MODE 0: f32 out. MODE 3: fused QKV (rope Q/K, transpose V), NY=48.

template<int MODE>
__global__ __launch_bounds__(256, 3)
void gemm97(const bf16_t* __restrict__ A,
            const bf16_t* __restrict__ B0,
            float* __restrict__ outF,
            bf16_t* __restrict__ outQ,
            bf16_t* __restrict__ outK,
            bf16_t* __restrict__ outV,
            const float* __restrict__ cosT,
            const float* __restrict__ sinT) {
    __shared__ __align__(16) bf16_t As[128 * 64];
    __shared__ __align__(16) bf16_t Bs[128 * 64];

    const int tid = threadIdx.x;
    const int l = tid & 63;
    const int w = tid >> 6;           // 0..3
    const int wr = w >> 1, wc = w & 1;
    const int lr = l & 15, lg = l >> 4;

    const int rowBase = blockIdx.x * 128;
    const int ct = blockIdx.y;

    const bf16_t* Ap = A + (size_t)rowBase * DIM;
    const bf16_t* Bp = B0 + (size_t)ct * 128 * DIM;

    f32x4 acc[4][4] = {};

    for (int kt = 0; kt < DIM; kt += 64) {
        // stage A and B tiles (16 KB each): 4 gload_lds per operand
#pragma unroll
        for (int t2 = 0; t2 < 4; ++t2) {
            int s = t2 * 256 + tid;
            int r = s >> 3, c = s & 7;
            int src = r * DIM + kt + ((c ^ (r & 7)) * 8);
            gload_lds16(Ap + src, As + (size_t)(t2 * 256 + w * 64) * 8);
            gload_lds16(Bp + src, Bs + (size_t)(t2 * 256 + w * 64) * 8);
        }
        __syncthreads();   // vmcnt(0)+lgkm(0)+barrier: tile landed

#pragma unroll
        for (int kk = 0; kk < 2; ++kk) {
            bf16x8 a[4], b[4];
#pragma unroll
            for (int mi = 0; mi < 4; ++mi) {
                int r = wr * 64 + mi * 16 + lr;
                a[mi] = *(const bf16x8*)(As + r * 64 + ((kk * 4 + lg) ^ (r & 7)) * 8);
            }
#pragma unroll
            for (int ni = 0; ni < 4; ++ni) {
                int r = wc * 64 + ni * 16 + lr;
                b[ni] = *(const bf16x8*)(Bs + r * 64 + ((kk * 4 + lg) ^ (r & 7)) * 8);
            }
            __builtin_amdgcn_s_setprio(1);
#pragma unroll
            for (int mi = 0; mi < 4; ++mi)
#pragma unroll
                for (int ni = 0; ni < 4; ++ni)
                    acc[mi][ni] = __builtin_amdgcn_mfma_f32_16x16x32_bf16(
                        a[mi], b[ni], acc[mi][ni], 0, 0, 0);
            __builtin_amdgcn_s_setprio(0);
        }
        __syncthreads();   // all reads drained: safe to overwrite buffer
    }

    // ---- epilogue ----
#pragma unroll
    for (int mi = 0; mi < 4; ++mi) {
        int gmBase = rowBase + wr * 64 + mi * 16 + lg * 4;
#pragma unroll
        for (int ni = 0; ni < 4; ++ni) {
            f32x4 v4 = acc[mi][ni];
            int gn = ct * 128 + wc * 64 + ni * 16 + lr;
            if (MODE == 0) {
#pragma unroll
                for (int i = 0; i < 4; ++i)
                    outF[(size_t)(gmBase + i) * DIM + gn] = v4[i];
            } else { // MODE 3: fused QKV, N = 6144
                if (gn < 4096) {          // Q rope -> Qr[b][h][s][d]
                    int h = gn >> 7, d = gn & 127, pi2 = d >> 1;
#pragma unroll
                    for (int i = 0; i < 4; ++i) {
                        float v = v4[i];
                        float pvv = __shfl_xor(v, 1);
                        int gm = gmBase + i;
                        int bb = gm >> 11, sidx = gm & (SEQ - 1);
                        float c = cosT[sidx * 64 + pi2], sn = sinT[sidx * 64 + pi2];
                        float o = (d & 1) ? (pvv * sn + v * c) : (v * c - pvv * sn);
                        outQ[((size_t)(bb * NH + h) * SEQ + sidx) * HD + d] = (bf16_t)o;
                    }
                } else if (gn < 5120) {   // K rope -> Kr[b][kvh][s][d]
                    int kn = gn - 4096;
                    int h = kn >> 7, d = kn & 127, pi2 = d >> 1;
#pragma unroll
                    for (int i = 0; i < 4; ++i) {
                        float v = v4[i];
                        float pvv = __shfl_xor(v, 1);
                        int gm = gmBase + i;
                        int bb = gm >> 11, sidx = gm & (SEQ - 1);
                        float c = cosT[sidx * 64 + pi2], sn = sinT[sidx * 64 + pi2];
                        float o = (d & 1) ? (pvv * sn + v * c) : (v * c - pvv * sn);
                        outK[((size_t)(bb * NKVH + h) * SEQ + sidx) * HD + d] = (bf16_t)o;
                    }
                } else {                  // V transpose -> Vt[b][kvh][d][s]
                    int vn = gn - 5120;
                    int kvh = vn >> 7, d = vn & 127;
#pragma unroll
                    for (int i = 0; i < 4; ++i) {
                        float dummy = __shfl_xor(v4[i], 1); (void)dummy;
                        int gm = gmBase + i;
                        int bb = gm >> 11, sidx = gm & (SEQ - 1);
                        outV[((size_t)(bb * NKVH + kvh) * HD + d) * SEQ + sidx] = (bf16_t)v4[i];
                    }
                }
            }
        }
    }
}

// ---------------- flash attention (causal, GQA) + defer-max (T13) ----------
__global__ __launch_bounds__(256, 2)
void attn_fwd(const bf16_t* __restrict__ Qr,
              const bf16_t* __restrict__ Kr,
              const bf16_t* __restrict__ Vt,
              bf16_t* __restrict__ Ob) {
    __shared__ __align__(16) bf16_t Ks[2][64 * 128];   // [kv][d], swizzled
    __shared__ __align__(16) bf16_t Vs[2][128 * 64];   // [d][kv], swizzled
    __shared__ __align__(16) bf16_t Ps[4][32 * 64];    // per-wave P, swizzled

    const int tid = threadIdx.x;
    const int l  = tid & 63;
    const int w  = tid >> 6;
    const int lr = l & 15, lg = l >> 4;
    const int e  = lr & 7;

    const int qt  = 15 - (blockIdx.x >> 6);
    const int bh  = blockIdx.x & 63;
    const int b   = bh >> 5;
    const int h   = bh & 31;
    const int kvh = h >> 2;
    const int q0  = qt * 128;
    const int nt  = 2 * qt + 2;
    const int qmin = q0 + w * 32;

    const bf16_t* kbase = Kr + (size_t)(b * NKVH + kvh) * SEQ * HD;
    const bf16_t* vbase = Vt + (size_t)(b * NKVH + kvh) * HD * SEQ;

    bf16x8 qf[2][4];
    const bf16_t* qp = Qr + ((size_t)(b * NH + h) * SEQ + qmin + lr) * HD;
#pragma unroll
    for (int mi = 0; mi < 2; ++mi)
#pragma unroll
        for (int kk = 0; kk < 4; ++kk)
            qf[mi][kk] = *(const bf16x8*)(qp + (size_t)mi * 16 * HD + kk * 32 + lg * 8);

    f32x4 oacc[2][8] = {};
    float mrow[2] = {-1e30f, -1e30f};
    float lsum[2] = {0.f, 0.f};

#pragma unroll
    for (int t2 = 0; t2 < 4; ++t2) {
        int s = t2 * 256 + tid;
        { int r = s >> 4, g = (s & 15) ^ (r & 7);
          gload_lds16(kbase + (size_t)r * HD + g * 8,
                      &Ks[0][(size_t)(t2 * 256 + w * 64) * 8]); }
        { int r = s >> 3, g = (s & 7) ^ (r & 7);
          gload_lds16(vbase + (size_t)r * SEQ + g * 8,
                      &Vs[0][(size_t)(t2 * 256 + w * 64) * 8]); }
    }
    __syncthreads();

    int cur = 0;
    for (int t = 0; t < nt; ++t) {
        if (t + 1 < nt) {
            const int kv1 = (t + 1) * 64;
#pragma unroll
            for (int t2 = 0; t2 < 4; ++t2) {
                int s = t2 * 256 + tid;
                { int r = s >> 4, g = (s & 15) ^ (r & 7);
                  gload_lds16(kbase + (size_t)(kv1 + r) * HD + g * 8,
                              &Ks[cur ^ 1][(size_t)(t2 * 256 + w * 64) * 8]); }
                { int r = s >> 3, g = (s & 7) ^ (r & 7);
                  gload_lds16(vbase + (size_t)r * SEQ + kv1 + g * 8,
                              &Vs[cur ^ 1][(size_t)(t2 * 256 + w * 64) * 8]); }
            }
        }

        const bool active = (t * 64) <= (qmin + 31);
        if (active) {
            const bool needMask = (t * 64 + 63) > qmin;

            f32x4 sf[2][4] = {};
#pragma unroll
            for (int kk = 0; kk < 4; ++kk)
#pragma unroll
                for (int nf = 0; nf < 4; ++nf) {
                    bf16x8 kf = *(const bf16x8*)(
                        &Ks[cur][(nf * 16 + lr) * 128 + ((kk * 4 + lg) ^ e) * 8]);
#pragma unroll
                    for (int mi = 0; mi < 2; ++mi)
                        sf[mi][nf] = __builtin_amdgcn_mfma_f32_16x16x32_bf16(
                            kf, qf[mi][kk], sf[mi][nf], 0, 0, 0);
                }

#pragma unroll
            for (int mi = 0; mi < 2; ++mi) {
                const int qrow = qmin + mi * 16 + lr;
                float mt = -1e30f;
#pragma unroll
                for (int nf = 0; nf < 4; ++nf)
#pragma unroll
                    for (int i = 0; i < 4; ++i) {
                        float sc = sf[mi][nf][i] * SCALE;
                        if (needMask && (t * 64 + nf * 16 + lg * 4 + i) > qrow)
                            sc = -1e30f;
                        sf[mi][nf][i] = sc;
                        mt = fmaxf(mt, sc);
                    }
                mt = fmaxf(mt, __shfl_xor(mt, 16));
                mt = fmaxf(mt, __shfl_xor(mt, 32));

                // T13 defer-max: skip the O-rescale when the tile max does not
                // exceed the running max by more than 8 (P bounded by e^8;
                // relative fp precision unaffected; lsum/oacc scale together).
                const bool skip = __all(mt - mrow[mi] <= 8.0f);
                const float mnew = skip ? mrow[mi] : fmaxf(mrow[mi], mt);

                float rs = 0.f;
#pragma unroll
                for (int nf = 0; nf < 4; ++nf)
#pragma unroll
                    for (int i = 0; i < 4; ++i) {
                        float p = __expf(sf[mi][nf][i] - mnew);
                        sf[mi][nf][i] = p;
                        rs += p;
                    }
                rs += __shfl_xor(rs, 16);
                rs += __shfl_xor(rs, 32);

                if (skip) {
                    lsum[mi] += rs;
                } else {
                    float alpha = __expf(mrow[mi] - mnew);
                    mrow[mi] = mnew;
                    lsum[mi] = lsum[mi] * alpha + rs;
                    float aO[4];
#pragma unroll
                    for (int i = 0; i < 4; ++i)
                        aO[i] = __shfl(alpha, lg * 4 + i);
#pragma unroll
                    for (int df = 0; df < 8; ++df)
#pragma unroll
                        for (int i = 0; i < 4; ++i)
                            oacc[mi][df][i] *= aO[i];
                }
            }

#pragma unroll
            for (int mi = 0; mi < 2; ++mi)
#pragma unroll
                for (int nf = 0; nf < 4; ++nf) {
                    union { bf16_t bb[4]; uint2 u; } pk;
#pragma unroll
                    for (int i = 0; i < 4; ++i) pk.bb[i] = (bf16_t)sf[mi][nf][i];
                    int addr = (mi * 16 + lr) * 64 +
                               (((nf * 2 + (lg >> 1)) ^ e) << 3) + (lg & 1) * 4;
                    *(uint2*)(&Ps[w][addr]) = pk.u;
                }
            asm volatile("s_waitcnt lgkmcnt(0)" ::: "memory");
            __builtin_amdgcn_sched_barrier(0);

            bf16x8 pf[2][2];
#pragma unroll
            for (int mi = 0; mi < 2; ++mi)
#pragma unroll
                for (int k2 = 0; k2 < 2; ++k2)
                    pf[mi][k2] = *(const bf16x8*)(
                        &Ps[w][(mi * 16 + lr) * 64 + ((k2 * 4 + lg) ^ e) * 8]);
#pragma unroll
            for (int df = 0; df < 8; ++df)
#pragma unroll
                for (int k2 = 0; k2 < 2; ++k2) {
                    bf16x8 vf = *(const bf16x8*)(
                        &Vs[cur][(df * 16 + lr) * 64 + ((k2 * 4 + lg) ^ e) * 8]);
#pragma unroll
                    for (int mi = 0; mi < 2; ++mi)
                        oacc[mi][df] = __builtin_amdgcn_mfma_f32_16x16x32_bf16(
                            pf[mi][k2], vf, oacc[mi][df], 0, 0, 0);
                }
        }
        __syncthreads();
        cur ^= 1;
    }

#pragma unroll
    for (int mi = 0; mi < 2; ++mi) {
        float ls[4];
#pragma unroll
        for (int i = 0; i < 4; ++i)
            ls[i] = 1.f / __shfl(lsum[mi], lg * 4 + i);
#pragma unroll
        for (int df = 0; df < 8; ++df)
#pragma unroll
            for (int i = 0; i < 4; ++i) {
                float o = oacc[mi][df][i] * ls[i];
                int gm = b * SEQ + qmin + mi * 16 + lg * 4 + i;
                int gn = h * HD + df * 16 + lr;
                Ob[(size_t)gm * DIM + gn] = (bf16_t)o;
            }
    }
}

// ---------------- launcher ----------------
extern "C" void kernel_launch(void* const* d_in, const int* in_sizes, int n_in,
                              void* d_out, int out_size, void* d_ws, size_t ws_size,
                              hipStream_t stream) {
    const float* x    = (const float*)d_in[0];
    const float* cosT = (const float*)d_in[1];
    const float* sinT = (const float*)d_in[2];
    const float* wq   = (const float*)d_in[3];
    const float* wk   = (const float*)d_in[4];
    const float* wv   = (const float*)d_in[5];
    const float* wo   = (const float*)d_in[6];

    bf16_t* p = (bf16_t*)d_ws;
    bf16_t* xb  = p; p += (size_t)MTOT * DIM;
    bf16_t* wb  = p; p += (size_t)(DIM + 2 * NKVH * HD + DIM) * DIM;  // wq|wk|wv|wo
    bf16_t* Qr  = p; p += (size_t)MTOT * DIM;
    bf16_t* Kr  = p; p += (size_t)BATCH * NKVH * SEQ * HD;
    bf16_t* Vt  = p; p += (size_t)BATCH * NKVH * HD * SEQ;
    bf16_t* Ob  = p; p += (size_t)MTOT * DIM;

    bf16_t* wob = wb + (size_t)(DIM + 2 * NKVH * HD) * DIM;  // wo region

    // one fused convert: x|wq|wk|wv|wo -> xb..wb (contiguous)
    cvt_all<<<2048, 256, 0, stream>>>(x, wq, wk, wv, wo, xb);

    // fused QKV: N = 4096 (Q) + 1024 (K) + 1024 (V) = 6144 -> 48 col tiles
    gemm97<3><<<dim3(32, 48), 256, 0, stream>>>(
        xb, wb, nullptr, Qr, Kr, Vt, cosT, sinT);

    attn_fwd<<<1024, 256, 0, stream>>>(Qr, Kr, Vt, Ob);

    gemm97<0><<<dim3(32, 32), 256, 0, stream>>>(
        Ob, wob, (float*)d_out, nullptr, nullptr, nullptr, nullptr, nullptr);
}